// Round 11
// baseline (478.242 us; speedup 1.0000x reference)
//
#include <hip/hip_runtime.h>

#define NROWS 32768
#define DIM   1024
#define HIDD  512
#define M3    (3*NROWS)

using bf16x8 = __attribute__((ext_vector_type(8))) short;
using f32x4  = __attribute__((ext_vector_type(4))) float;

#define MFMA16(a,b,c) __builtin_amdgcn_mfma_f32_16x16x32_bf16(a,b,c,0,0,0)
#define WAIT_VM(N)  asm volatile("s_waitcnt vmcnt(" #N ")" ::: "memory")
#define WAIT_LGKM0  asm volatile("s_waitcnt lgkmcnt(0)" ::: "memory")
#define MEMFENCE    asm volatile("" ::: "memory")
#define BAR()       __builtin_amdgcn_s_barrier()
#define SCHEDB()    __builtin_amdgcn_sched_barrier(0)
#define SP1()       __builtin_amdgcn_s_setprio(1)
#define SP0()       __builtin_amdgcn_s_setprio(0)

// ---------- helpers ----------
static __device__ __forceinline__ unsigned short f2bf(float f) {
    unsigned u = __float_as_uint(f);
    u += 0x7FFFu + ((u >> 16) & 1u);   // round-to-nearest-even
    return (unsigned short)(u >> 16);
}
static __device__ __forceinline__ float bf2f(unsigned short s) {
    return __uint_as_float(((unsigned)s) << 16);
}
static __device__ __forceinline__ unsigned cvtpk(float a, float b) {
    unsigned r;
    asm("v_cvt_pk_bf16_f32 %0, %1, %2" : "=v"(r) : "v"(a), "v"(b));
    return r;
}
static __device__ __forceinline__ void gload16(const void* gsrc, void* ldst) {
    __builtin_amdgcn_global_load_lds(
        (const __attribute__((address_space(1))) unsigned int*)gsrc,
        (__attribute__((address_space(3))) unsigned int*)ldst,
        16, 0, 0);
}

// ---------- convert fp32 -> bf16 (for W1) ----------
__global__ __launch_bounds__(256)
void cvt_kernel(const float* __restrict__ src, unsigned short* __restrict__ dst, int n4)
{
    const int i = blockIdx.x * 256 + threadIdx.x;
    if (i < n4) {
        float4 v = reinterpret_cast<const float4*>(src)[i];
        uint2 o;
        o.x = cvtpk(v.x, v.y);
        o.y = cvtpk(v.z, v.w);
        reinterpret_cast<uint2*>(dst)[i] = o;
    }
}

// ---------- Gram: G = W2^T W2 (bf16 out). grid (16,16), 32x32 tile, 2x2/thread ----------
__global__ __launch_bounds__(256)
void gram_kernel(const float* __restrict__ W2, unsigned short* __restrict__ Gbf)
{
    __shared__ float Wi[32][32];
    __shared__ float Wj[32][32];
    const int i0 = blockIdx.x * 32, j0 = blockIdx.y * 32;
    const int tid = threadIdx.x;
    const int kq = tid >> 3, c4 = (tid & 7) * 4;
    const int ti = (tid & 15) * 2, tj = (tid >> 4) * 2;
    float s00 = 0.f, s01 = 0.f, s10 = 0.f, s11 = 0.f;
    for (int k0 = 0; k0 < DIM; k0 += 32) {
        *reinterpret_cast<float4*>(&Wi[kq][c4]) =
            *reinterpret_cast<const float4*>(&W2[(size_t)(k0 + kq) * HIDD + i0 + c4]);
        *reinterpret_cast<float4*>(&Wj[kq][c4]) =
            *reinterpret_cast<const float4*>(&W2[(size_t)(k0 + kq) * HIDD + j0 + c4]);
        __syncthreads();
        #pragma unroll
        for (int k = 0; k < 32; ++k) {
            const float2 a = *reinterpret_cast<const float2*>(&Wi[k][ti]);
            const float2 b = *reinterpret_cast<const float2*>(&Wj[k][tj]);
            s00 = fmaf(a.x, b.x, s00); s01 = fmaf(a.x, b.y, s01);
            s10 = fmaf(a.y, b.x, s10); s11 = fmaf(a.y, b.y, s11);
        }
        __syncthreads();
    }
    *reinterpret_cast<unsigned*>(&Gbf[(size_t)(i0 + ti) * HIDD + j0 + tj])     = cvtpk(s00, s01);
    *reinterpret_cast<unsigned*>(&Gbf[(size_t)(i0 + ti + 1) * HIDD + j0 + tj]) = cvtpk(s10, s11);
}

// ---------- w2b = W2^T b2 (fp32). grid (8,4) x 64 thr, k-split + atomics (w2b pre-zeroed) ----------
__global__ __launch_bounds__(64)
void w2b_kernel(const float* __restrict__ W2, const float* __restrict__ b2,
                float* __restrict__ w2b)
{
    const int c = blockIdx.x * 64 + threadIdx.x;
    const int m0 = blockIdx.y * 256;
    float acc = 0.f;
    for (int m = m0; m < m0 + 256; ++m)
        acc = fmaf(W2[(size_t)m * HIDD + c], b2[m], acc);
    atomicAdd(&w2b[c], acc);
}

// ---------- GEMM1 (R3-verified structure): h = leaky(bn(x @ W1^T + b1)) ----------
// 3072 blocks, XCD-swizzled. 128x128 tile, BK=64, 4 waves each own 64x64 (4x4 frags).
__global__ __launch_bounds__(256)
void gemm1_mfma(const float* __restrict__ x0, const float* __restrict__ x1,
                const float* __restrict__ x2,
                const unsigned short* __restrict__ W1bf,
                const float* __restrict__ b1, const float* __restrict__ gamma,
                const float* __restrict__ beta, const float* __restrict__ rmean,
                const float* __restrict__ rvar,
                unsigned short* __restrict__ h)
{
    __shared__ unsigned short Abuf[128*64];      // [r][64], byte ^((r&7)<<4)
    __shared__ unsigned short Bbuf[2*128*32];    // [panel][col][32], chunk-permuted

    const int lin = blockIdx.x;                  // 3072 = 8 XCD * 384
    const int wgid = (lin & 7) * 384 + (lin >> 3);
    const int cb = wgid & 3;
    const int rb = wgid >> 2;
    const int tid  = threadIdx.x;
    const int lane = tid & 63, w = tid >> 6;
    const int wr = w >> 1, wc = w & 1;
    const int row0 = rb * 128;
    const int s = row0 >> 15;
    const float* x = (s == 0) ? x0 : (s == 1 ? x1 : x2);
    const int rl0 = row0 & (NROWS - 1);
    const int col0 = cb * 128;
    const int l15 = lane & 15, lq = lane >> 4;

    f32x4 acc[4][4] = {};
    float4 aR[8];

    #pragma unroll
    for (int p = 0; p < 8; ++p) {
        const int f = p * 256 + tid;
        const int r = f >> 4, c4 = f & 15;
        aR[p] = *reinterpret_cast<const float4*>(&x[(size_t)(rl0 + r) * DIM + c4 * 4]);
    }

    for (int t = 0; t < 16; ++t) {
        const int k0 = t * 64;
        #pragma unroll
        for (int p = 0; p < 8; ++p) {
            const int f = p * 256 + tid;
            const int r = f >> 4, c4 = f & 15;
            const unsigned off = (unsigned)((r * 128 + c4 * 8) ^ ((r & 7) << 4));
            uint2 o;
            o.x = cvtpk(aR[p].x, aR[p].y);
            o.y = cvtpk(aR[p].z, aR[p].w);
            *reinterpret_cast<uint2*>(reinterpret_cast<char*>(Abuf) + off) = o;
        }
        #pragma unroll
        for (int c = 0; c < 4; ++c) {
            const int f = c * 256 + tid;
            const int panel = f >> 9;
            const int cc = (f >> 2) & 127;
            const int chunk = (f & 3) ^ ((cc >> 1) & 3);
            gload16(&W1bf[(size_t)(col0 + cc) * DIM + k0 + panel * 32 + chunk * 8],
                    reinterpret_cast<char*>(Bbuf) + (size_t)f * 16);
        }
        __syncthreads();
        if (t < 15) {
            #pragma unroll
            for (int p = 0; p < 8; ++p) {
                const int f = p * 256 + tid;
                const int r = f >> 4, c4 = f & 15;
                aR[p] = *reinterpret_cast<const float4*>(
                    &x[(size_t)(rl0 + r) * DIM + k0 + 64 + c4 * 4]);
            }
        }
        bf16x8 bfv[2][4];
        #pragma unroll
        for (int kk = 0; kk < 2; ++kk)
            #pragma unroll
            for (int n = 0; n < 4; ++n) {
                const int colr = wc*64 + n*16 + l15;
                const int slq = lq ^ ((colr >> 1) & 3);
                bfv[kk][n] = *reinterpret_cast<const bf16x8*>(
                    reinterpret_cast<char*>(Bbuf) + kk*8192 + colr*64 + slq*16);
            }
        #pragma unroll
        for (int kk = 0; kk < 2; ++kk)
            #pragma unroll
            for (int m = 0; m < 4; ++m) {
                const int row = wr*64 + m*16 + l15;
                const unsigned ab = (unsigned)((row*128 + kk*64 + lq*16) ^ ((row & 7) << 4));
                bf16x8 af = *reinterpret_cast<const bf16x8*>(
                    reinterpret_cast<char*>(Abuf) + ab);
                #pragma unroll
                for (int n = 0; n < 4; ++n)
                    acc[m][n] = MFMA16(af, bfv[kk][n], acc[m][n]);
            }
        __syncthreads();
    }

    float As[4], Bsc[4];
    #pragma unroll
    for (int n = 0; n < 4; ++n) {
        const int c = col0 + wc*64 + n*16 + l15;
        const float inv = rsqrtf(rvar[c] + 1e-5f);
        As[n]  = inv * gamma[c];
        Bsc[n] = (b1[c] - rmean[c]) * As[n] + beta[c];
    }
    #pragma unroll
    for (int m = 0; m < 4; ++m) {
        const int rbase = row0 + wr*64 + m*16 + lq*4;
        #pragma unroll
        for (int n = 0; n < 4; ++n) {
            const int c = col0 + wc*64 + n*16 + l15;
            #pragma unroll
            for (int i = 0; i < 4; ++i) {
                float v = fmaf(acc[m][n][i], As[n], Bsc[n]);
                v = (v >= 0.f) ? v : 0.1f * v;
                h[(size_t)(rbase + i) * HIDD + c] = f2bf(v);
            }
        }
    }
}

// ---------- GEMM2' (Gram, 8-phase): U = H·G; distances + L2 via dots with h ----------
// 2048 blocks XCD-swizzled, 512 thr / 8 waves. Tile: M=192 (64 rows x 3 streams),
// N=128 U-cols (of 512), BK=64, 8 K-tiles. Half the FLOPs of the e-based gemm2.
__global__ __launch_bounds__(512, 1)
void gemm2_mfma(const unsigned short* __restrict__ h,
                const unsigned short* __restrict__ Gbf,
                const float* __restrict__ w2b,
                float* __restrict__ pdp, float* __restrict__ pdn,
                float* __restrict__ pl2)
{
    __shared__ char smem[81920];
    char* const Ab = smem;            // 2 x 24576: A[par][mrow 192][k 64]
    char* const Bb = smem + 49152;    // 2 x 16384: B[par][col 128][k 64]

    const int lin = blockIdx.x;       // 2048 = 8 XCD * 256
    const int wgid = (lin & 7) * 256 + (lin >> 3);
    const int cb = wgid & 3;          // 128-col tile of 512
    const int rb = wgid >> 2;         // 0..511
    const int tid  = threadIdx.x;
    const int lane = tid & 63, w = tid >> 6;
    const int wm = w >> 2, wn = w & 3;
    const int row0 = rb * 64;
    const int col0 = cb * 128;
    const int l15 = lane & 15, lq = lane >> 4;

    f32x4 acc[6][2] = {};             // [mh*3 + stream][nf]

    auto issueA = [&](int k0, char* Adst) {
        #pragma unroll
        for (int i = 0; i < 3; ++i) {
            const int f = i * 512 + tid;       // 0..1535
            const int mrow = f >> 3, c = f & 7;
            const int mf = mrow >> 4, rr = mrow & 15;
            const int ss = mf % 3, rf = mf / 3;
            gload16(&h[((size_t)ss * NROWS + row0 + rf * 16 + rr) * HIDD + k0 + ((c ^ (mrow & 7)) << 3)],
                    Adst + f * 16);
        }
    };
    auto issueB = [&](int k0, char* Bdst) {
        #pragma unroll
        for (int i = 0; i < 2; ++i) {
            const int f = i * 512 + tid;       // 0..1023
            const int col = f >> 3, c = f & 7;
            gload16(&Gbf[(size_t)(col0 + col) * HIDD + k0 + ((c ^ (col & 7)) << 3)],
                    Bdst + f * 16);
        }
    };
    auto readA = [&](bf16x8 (&a)[3][2], int mh, char* Abase) {
        #pragma unroll
        for (int mm = 0; mm < 3; ++mm) {
            const int row = (wm * 6 + mh * 3 + mm) * 16 + l15;
            const int swz = (row & 7) << 4;
            #pragma unroll
            for (int ks = 0; ks < 2; ++ks)
                a[mm][ks] = *reinterpret_cast<const bf16x8*>(
                    Abase + ((row * 128 + ks * 64 + lq * 16) ^ swz));
        }
    };
    auto readB = [&](bf16x8 (&b)[2], int nh, char* Bbase) {
        const int col = wn * 32 + nh * 16 + l15;
        const int swz = (col & 7) << 4;
        #pragma unroll
        for (int ks = 0; ks < 2; ++ks)
            b[ks] = *reinterpret_cast<const bf16x8*>(
                Bbase + ((col * 128 + ks * 64 + lq * 16) ^ swz));
    };

    // ---- prologue ----
    issueA(0, Ab);
    MEMFENCE;
    issueB(0, Bb);
    WAIT_VM(0);
    BAR();

    for (int t = 0; t < 8; ++t) {
        char* const Apt = Ab + (t & 1) * 24576;
        char* const Apn = Ab + ((t & 1) ^ 1) * 24576;
        char* const Bpt = Bb + (t & 1) * 16384;
        char* const Bpn = Bb + ((t & 1) ^ 1) * 16384;
        const int kn = ((t < 7) ? (t + 1) : 7) * 64;

        bf16x8 a[3][2], b[2], a2[3][2];
        // ---- P1: (mh0, nh0); issue A(t+1)+B(t+1) ----
        readA(a, 0, Apt);
        readB(b, 0, Bpt);
        issueA(kn, Apn);
        MEMFENCE;
        issueB(kn, Bpn);
        BAR(); WAIT_LGKM0; SCHEDB(); SP1();
        #pragma unroll
        for (int mm = 0; mm < 3; ++mm)
            #pragma unroll
            for (int ks = 0; ks < 2; ++ks)
                acc[mm][0] = MFMA16(a[mm][ks], b[ks], acc[mm][0]);
        SP0(); BAR();
        // ---- P2: (mh0, nh1) ----
        readB(b, 1, Bpt);
        BAR(); WAIT_LGKM0; SCHEDB(); SP1();
        #pragma unroll
        for (int mm = 0; mm < 3; ++mm)
            #pragma unroll
            for (int ks = 0; ks < 2; ++ks)
                acc[mm][1] = MFMA16(a[mm][ks], b[ks], acc[mm][1]);
        SP0(); BAR();
        // ---- P3: (mh1, nh1) ----
        readA(a2, 1, Apt);
        BAR(); WAIT_LGKM0; SCHEDB(); SP1();
        #pragma unroll
        for (int mm = 0; mm < 3; ++mm)
            #pragma unroll
            for (int ks = 0; ks < 2; ++ks)
                acc[3 + mm][1] = MFMA16(a2[mm][ks], b[ks], acc[3 + mm][1]);
        SP0(); BAR();
        // ---- P4: (mh1, nh0); drain prefetches (3 phases of cover) ----
        readB(b, 0, Bpt);
        WAIT_VM(0);
        BAR(); WAIT_LGKM0; SCHEDB(); SP1();
        #pragma unroll
        for (int mm = 0; mm < 3; ++mm)
            #pragma unroll
            for (int ks = 0; ks < 2; ++ks)
                acc[3 + mm][0] = MFMA16(a2[mm][ks], b[ks], acc[3 + mm][0]);
        SP0(); BAR();
    }

    // ---- epilogue: restage FULL h slice [3][64 r][128 c] padded in LDS ----
    // 3 x 64 x 16 chunks(16B) = 3072; 6/thread. Row stride 272 B (256 data + 16 pad);
    // stream stride 17408 B; total 52224 B. l2red moved past it (53248).
    uint4 hv[6]; int hoff[6];
    #pragma unroll
    for (int i = 0; i < 6; ++i) {
        const int f = i * 512 + tid;          // 0..3071
        const int ss = f >> 10, rem = f & 1023, r = rem >> 4, c16 = rem & 15;
        hv[i] = *reinterpret_cast<const uint4*>(
            &h[((size_t)ss * NROWS + row0 + r) * HIDD + col0 + c16 * 8]);
        hoff[i] = ss * 17408 + r * 272 + c16 * 16;
    }
    __syncthreads();
    #pragma unroll
    for (int i = 0; i < 6; ++i)
        *reinterpret_cast<uint4*>(smem + hoff[i]) = hv[i];
    __syncthreads();

    float w2b2[2];
    w2b2[0] = 2.f * w2b[col0 + wn * 32 + l15];
    w2b2[1] = 2.f * w2b[col0 + wn * 32 + 16 + l15];
    float l2t = 0.f;
    #pragma unroll
    for (int mh = 0; mh < 2; ++mh) {
        #pragma unroll
        for (int i = 0; i < 4; ++i) {
            const int r_loc = (wm * 2 + mh) * 16 + lq * 4 + i;
            float dp = 0.f, dn = 0.f;
            #pragma unroll
            for (int nf = 0; nf < 2; ++nf) {
                const int c_loc = wn * 32 + nf * 16 + l15;
                const int hb = r_loc * 272 + c_loc * 2;
                const float ha = bf2f(*reinterpret_cast<const unsigned short*>(smem + hb));
                const float hp = bf2f(*reinterpret_cast<const unsigned short*>(smem + 17408 + hb));
                const float hn = bf2f(*reinterpret_cast<const unsigned short*>(smem + 34816 + hb));
                const float ua = acc[mh * 3 + 0][nf][i];
                const float up = acc[mh * 3 + 1][nf][i];
                const float un = acc[mh * 3 + 2][nf][i];
                dp += (ua - up) * (ha - hp);
                dn += (ua - un) * (ha - hn);
                l2t += (ua + w2b2[nf]) * ha + (up + w2b2[nf]) * hp + (un + w2b2[nf]) * hn;
            }
            #pragma unroll
            for (int mm = 1; mm < 16; mm <<= 1) {
                dp += __shfl_xor(dp, mm);
                dn += __shfl_xor(dn, mm);
            }
            if (l15 == 0) {
                pdp[(size_t)(cb * 4 + wn) * NROWS + row0 + r_loc] = dp;
                pdn[(size_t)(cb * 4 + wn) * NROWS + row0 + r_loc] = dn;
            }
        }
    }
    #pragma unroll
    for (int mm = 1; mm < 64; mm <<= 1) l2t += __shfl_xor(l2t, mm);
    float* const l2red = (float*)(smem + 53248);     // disjoint from h restage region
    if (lane == 0) l2red[w] = l2t;
    __syncthreads();
    if (tid == 0) {
        float t = 0.f;
        #pragma unroll
        for (int ww = 0; ww < 8; ++ww) t += l2red[ww];
        pl2[wgid] = t;
    }
}

// ---------- per-row margins ----------
__global__ __launch_bounds__(256)
void margins_kernel(const float* __restrict__ pdp, const float* __restrict__ pdn,
                    float* __restrict__ margins, float* __restrict__ dd)
{
    const int r = blockIdx.x * 256 + threadIdx.x;
    float dp2 = 0.f, dn2 = 0.f;
    #pragma unroll
    for (int q = 0; q < 16; ++q) {
        dp2 += pdp[(size_t)q * NROWS + r];
        dn2 += pdn[(size_t)q * NROWS + r];
    }
    dp2 = fmaxf(dp2, 0.f);
    dn2 = fmaxf(dn2, 0.f);
    dd[r] = dn2 - dp2;
    margins[r] = (dn2 < dp2) ? (sqrtf(dp2) - sqrtf(dn2)) : 0.f;
}

// ---------- final: l2 sum (+3N||b2||^2) + radix-select (parallel scan) + neighbor + loss ----------
__global__ __launch_bounds__(1024)
void final_kernel(const float* __restrict__ pl2, int npl2,
                  const float* __restrict__ b2,
                  const float* __restrict__ margins, const float* __restrict__ dd,
                  float* __restrict__ out)
{
    __shared__ unsigned hist[256];
    __shared__ float warp_red[16];
    __shared__ unsigned wsum[4];
    __shared__ unsigned sh_prefix;
    __shared__ int sh_k;
    __shared__ float sh_l2;
    __shared__ unsigned sh_cle;
    __shared__ unsigned sh_minAbove;
    const int tid = threadIdx.x;

    const float bb = b2[tid];                       // 1024 threads cover b2 exactly
    float l2 = 3.0f * (float)NROWS * bb * bb;
    for (int i = tid; i < npl2; i += 1024) l2 += pl2[i];
    #pragma unroll
    for (int m = 1; m < 64; m <<= 1) l2 += __shfl_xor(l2, m);
    if ((tid & 63) == 0) warp_red[tid >> 6] = l2;
    __syncthreads();
    if (tid == 0) {
        float t = 0.f;
        for (int w = 0; w < 16; ++w) t += warp_red[w];
        sh_l2 = t;
        sh_k = 8191; sh_prefix = 0u;
        sh_cle = 0u; sh_minAbove = 0xFFFFFFFFu;
    }
    __syncthreads();

    for (int shift = 24; shift >= 0; shift -= 8) {
        if (tid < 256) hist[tid] = 0u;
        __syncthreads();
        const unsigned prefix = sh_prefix;
        const int kcur = sh_k;
        const unsigned mask = (shift == 24) ? 0u : (0xFFFFFFFFu << (shift + 8));
        for (int i = tid; i < NROWS; i += 1024) {
            const unsigned key = __float_as_uint(margins[i]);
            if (((key ^ prefix) & mask) == 0u)
                atomicAdd(&hist[(key >> shift) & 255u], 1u);
        }
        __syncthreads();
        unsigned v = 0, cme = 0;
        if (tid < 256) {
            cme = hist[tid];
            v = cme;
            #pragma unroll
            for (int off = 1; off < 64; off <<= 1) {
                unsigned tt = __shfl_up(v, off);
                if ((tid & 63) >= off) v += tt;
            }
            if ((tid & 63) == 63) wsum[tid >> 6] = v;
        }
        __syncthreads();
        if (tid < 256) {
            unsigned wo = 0;
            for (int i = 0; i < (tid >> 6); ++i) wo += wsum[i];
            const unsigned incl = v + wo;
            const unsigned excl = incl - cme;
            if ((unsigned)kcur >= excl && (unsigned)kcur < incl) {
                sh_prefix = prefix | ((unsigned)tid << shift);
                sh_k = kcur - (int)excl;
            }
        }
        __syncthreads();
    }
    const unsigned p1u = sh_prefix;

    unsigned lc = 0, lmin = 0xFFFFFFFFu;
    for (int i = tid; i < NROWS; i += 1024) {
        const unsigned key = __float_as_uint(margins[i]);
        if (key <= p1u) ++lc; else lmin = min(lmin, key);
    }
    #pragma unroll
    for (int m = 1; m < 64; m <<= 1) {
        lc += __shfl_xor(lc, m);
        lmin = min(lmin, (unsigned)__shfl_xor((int)lmin, m));
    }
    if ((tid & 63) == 0) {
        atomicAdd(&sh_cle, lc);
        atomicMin(&sh_minAbove, lmin);
    }
    __syncthreads();
    const float p1 = __uint_as_float(p1u);
    const float p2 = (sh_cle >= 8193u) ? p1 : __uint_as_float(sh_minAbove);
    const float margin = p1 + 0.75f * (p2 - p1);

    float ssum = 0.f;
    for (int i = tid; i < NROWS; i += 1024) {
        const float t = dd[i] + margin;
        ssum += (t > 0.f) ? t : 0.f;
    }
    #pragma unroll
    for (int m = 1; m < 64; m <<= 1) ssum += __shfl_xor(ssum, m);
    if ((tid & 63) == 0) warp_red[tid >> 6] = ssum;
    __syncthreads();
    if (tid == 0) {
        float S = 0.f;
        for (int w = 0; w < 16; ++w) S += warp_red[w];
        out[0] = S / (float)NROWS + 1e-3f * sh_l2 / (float)NROWS;
    }
}

extern "C" void kernel_launch(void* const* d_in, const int* in_sizes, int n_in,
                              void* d_out, int out_size, void* d_ws, size_t ws_size,
                              hipStream_t stream) {
    (void)in_sizes; (void)n_in; (void)out_size; (void)ws_size;
    const float* item = (const float*)d_in[0];
    const float* pos  = (const float*)d_in[1];
    const float* neg  = (const float*)d_in[2];
    const float* W1   = (const float*)d_in[3];
    const float* b1   = (const float*)d_in[4];
    const float* gam  = (const float*)d_in[5];
    const float* bet  = (const float*)d_in[6];
    const float* rmu  = (const float*)d_in[7];
    const float* rvr  = (const float*)d_in[8];
    const float* W2   = (const float*)d_in[9];
    const float* b2   = (const float*)d_in[10];

    char* ws = (char*)d_ws;
    unsigned short* h = (unsigned short*)ws;
    size_t off = (size_t)M3 * HIDD * sizeof(unsigned short);
    unsigned short* W1bf = (unsigned short*)(ws + off); off += (size_t)HIDD * DIM * 2;
    unsigned short* Gbf  = (unsigned short*)(ws + off); off += (size_t)HIDD * HIDD * 2;
    float* w2b = (float*)(ws + off); off += (size_t)HIDD * 4;
    float* pdp = (float*)(ws + off); off += (size_t)16 * NROWS * 4;
    float* pdn = (float*)(ws + off); off += (size_t)16 * NROWS * 4;
    float* pl2 = (float*)(ws + off); off += (size_t)2048 * 4;
    float* margins = (float*)(ws + off); off += (size_t)NROWS * 4;
    float* dd = (float*)(ws + off); off += (size_t)NROWS * 4;

    hipMemsetAsync(w2b, 0, HIDD * sizeof(float), stream);
    cvt_kernel<<<dim3((HIDD*DIM/4 + 255)/256), 256, 0, stream>>>(W1, W1bf, HIDD*DIM/4);
    gram_kernel<<<dim3(16, 16), 256, 0, stream>>>(W2, Gbf);
    w2b_kernel<<<dim3(8, 4), 64, 0, stream>>>(W2, b2, w2b);
    gemm1_mfma<<<dim3(3072), 256, 0, stream>>>(
        item, pos, neg, W1bf, b1, gam, bet, rmu, rvr, h);
    gemm2_mfma<<<dim3(2048), 512, 0, stream>>>(
        h, Gbf, w2b, pdp, pdn, pl2);
    margins_kernel<<<dim3(NROWS/256), 256, 0, stream>>>(pdp, pdn, margins, dd);
    final_kernel<<<1, 1024, 0, stream>>>(pl2, 2048, b2, margins, dd, (float*)d_out);
}

// Round 12
// 440.370 us; speedup vs baseline: 1.0860x; 1.0860x over previous
//
#include <hip/hip_runtime.h>

#define NROWS 32768
#define DIM   1024
#define HIDD  512
#define M3    (3*NROWS)

using bf16x8 = __attribute__((ext_vector_type(8))) short;
using f32x4  = __attribute__((ext_vector_type(4))) float;

#define MFMA16(a,b,c) __builtin_amdgcn_mfma_f32_16x16x32_bf16(a,b,c,0,0,0)
#define WAIT_VM(N)  asm volatile("s_waitcnt vmcnt(" #N ")" ::: "memory")
#define WAIT_LGKM0  asm volatile("s_waitcnt lgkmcnt(0)" ::: "memory")
#define MEMFENCE    asm volatile("" ::: "memory")
#define BAR()       __builtin_amdgcn_s_barrier()
#define SCHEDB()    __builtin_amdgcn_sched_barrier(0)
#define SP1()       __builtin_amdgcn_s_setprio(1)
#define SP0()       __builtin_amdgcn_s_setprio(0)

// ---------- helpers ----------
static __device__ __forceinline__ unsigned short f2bf(float f) {
    unsigned u = __float_as_uint(f);
    u += 0x7FFFu + ((u >> 16) & 1u);   // round-to-nearest-even
    return (unsigned short)(u >> 16);
}
static __device__ __forceinline__ unsigned cvtpk(float a, float b) {
    unsigned r;
    asm("v_cvt_pk_bf16_f32 %0, %1, %2" : "=v"(r) : "v"(a), "v"(b));
    return r;
}
static __device__ __forceinline__ void gload16(const void* gsrc, void* ldst) {
    __builtin_amdgcn_global_load_lds(
        (const __attribute__((address_space(1))) unsigned int*)gsrc,
        (__attribute__((address_space(3))) unsigned int*)ldst,
        16, 0, 0);
}

// ---------- convert fp32 -> bf16 (for W1, W2) ----------
__global__ __launch_bounds__(256)
void cvt_kernel(const float* __restrict__ src, unsigned short* __restrict__ dst, int n4)
{
    const int i = blockIdx.x * 256 + threadIdx.x;
    if (i < n4) {
        float4 v = reinterpret_cast<const float4*>(src)[i];
        uint2 o;
        o.x = cvtpk(v.x, v.y);
        o.y = cvtpk(v.z, v.w);
        reinterpret_cast<uint2*>(dst)[i] = o;
    }
}

// ---------- GEMM1 (R3-verified structure + early-B-issue): h = leaky(bn(x @ W1^T + b1)) ----------
// 3072 blocks, XCD-swizzled. 128x128 tile, BK=64, 4 waves each own 64x64 (4x4 frags).
// Change vs R9: B gload16s issued BEFORE the A cvt/ds_write stage, so the A-stage VALU+DS
// work (~150-250 cyc) covers part of the B-gload latency otherwise exposed at the barrier.
__global__ __launch_bounds__(256)
void gemm1_mfma(const float* __restrict__ x0, const float* __restrict__ x1,
                const float* __restrict__ x2,
                const unsigned short* __restrict__ W1bf,
                const float* __restrict__ b1, const float* __restrict__ gamma,
                const float* __restrict__ beta, const float* __restrict__ rmean,
                const float* __restrict__ rvar,
                unsigned short* __restrict__ h)
{
    __shared__ unsigned short Abuf[128*64];      // [r][64], byte ^((r&7)<<4)
    __shared__ unsigned short Bbuf[2*128*32];    // [panel][col][32], chunk-permuted

    const int lin = blockIdx.x;                  // 3072 = 8 XCD * 384
    const int wgid = (lin & 7) * 384 + (lin >> 3);
    const int cb = wgid & 3;
    const int rb = wgid >> 2;
    const int tid  = threadIdx.x;
    const int lane = tid & 63, w = tid >> 6;
    const int wr = w >> 1, wc = w & 1;
    const int row0 = rb * 128;
    const int s = row0 >> 15;
    const float* x = (s == 0) ? x0 : (s == 1 ? x1 : x2);
    const int rl0 = row0 & (NROWS - 1);
    const int col0 = cb * 128;
    const int l15 = lane & 15, lq = lane >> 4;

    f32x4 acc[4][4] = {};
    float4 aR[8];

    #pragma unroll
    for (int p = 0; p < 8; ++p) {
        const int f = p * 256 + tid;
        const int r = f >> 4, c4 = f & 15;
        aR[p] = *reinterpret_cast<const float4*>(&x[(size_t)(rl0 + r) * DIM + c4 * 4]);
    }

    for (int t = 0; t < 16; ++t) {
        const int k0 = t * 64;
        // ---- stage B via global_load_lds FIRST (latency covered by A-stage below) ----
        #pragma unroll
        for (int c = 0; c < 4; ++c) {
            const int f = c * 256 + tid;
            const int panel = f >> 9;
            const int cc = (f >> 2) & 127;
            const int chunk = (f & 3) ^ ((cc >> 1) & 3);
            gload16(&W1bf[(size_t)(col0 + cc) * DIM + k0 + panel * 32 + chunk * 8],
                    reinterpret_cast<char*>(Bbuf) + (size_t)f * 16);
        }
        MEMFENCE;
        // ---- stage A (cvt from regs, XOR-swizzled) ----
        #pragma unroll
        for (int p = 0; p < 8; ++p) {
            const int f = p * 256 + tid;
            const int r = f >> 4, c4 = f & 15;
            const unsigned off = (unsigned)((r * 128 + c4 * 8) ^ ((r & 7) << 4));
            uint2 o;
            o.x = cvtpk(aR[p].x, aR[p].y);
            o.y = cvtpk(aR[p].z, aR[p].w);
            *reinterpret_cast<uint2*>(reinterpret_cast<char*>(Abuf) + off) = o;
        }
        __syncthreads();
        // ---- issue next A loads (drain hidden under MFMA at next barrier) ----
        if (t < 15) {
            #pragma unroll
            for (int p = 0; p < 8; ++p) {
                const int f = p * 256 + tid;
                const int r = f >> 4, c4 = f & 15;
                aR[p] = *reinterpret_cast<const float4*>(
                    &x[(size_t)(rl0 + r) * DIM + k0 + 64 + c4 * 4]);
            }
        }
        // ---- fragments + MFMA ----
        bf16x8 bfv[2][4];
        #pragma unroll
        for (int kk = 0; kk < 2; ++kk)
            #pragma unroll
            for (int n = 0; n < 4; ++n) {
                const int colr = wc*64 + n*16 + l15;
                const int slq = lq ^ ((colr >> 1) & 3);
                bfv[kk][n] = *reinterpret_cast<const bf16x8*>(
                    reinterpret_cast<char*>(Bbuf) + kk*8192 + colr*64 + slq*16);
            }
        #pragma unroll
        for (int kk = 0; kk < 2; ++kk)
            #pragma unroll
            for (int m = 0; m < 4; ++m) {
                const int row = wr*64 + m*16 + l15;
                const unsigned ab = (unsigned)((row*128 + kk*64 + lq*16) ^ ((row & 7) << 4));
                bf16x8 af = *reinterpret_cast<const bf16x8*>(
                    reinterpret_cast<char*>(Abuf) + ab);
                #pragma unroll
                for (int n = 0; n < 4; ++n)
                    acc[m][n] = MFMA16(af, bfv[kk][n], acc[m][n]);
            }
        __syncthreads();
    }

    // epilogue: BN(eval) + leaky folded to v*A + B per column
    float As[4], Bsc[4];
    #pragma unroll
    for (int n = 0; n < 4; ++n) {
        const int c = col0 + wc*64 + n*16 + l15;
        const float inv = rsqrtf(rvar[c] + 1e-5f);
        As[n]  = inv * gamma[c];
        Bsc[n] = (b1[c] - rmean[c]) * As[n] + beta[c];
    }
    #pragma unroll
    for (int m = 0; m < 4; ++m) {
        const int rbase = row0 + wr*64 + m*16 + lq*4;
        #pragma unroll
        for (int n = 0; n < 4; ++n) {
            const int c = col0 + wc*64 + n*16 + l15;
            #pragma unroll
            for (int i = 0; i < 4; ++i) {
                float v = fmaf(acc[m][n][i], As[n], Bsc[n]);
                v = (v >= 0.f) ? v : 0.1f * v;
                h[(size_t)(rbase + i) * HIDD + c] = f2bf(v);
            }
        }
    }
}

// ---------- GEMM2 (8-phase fused, R6/R9 best-measured): e = h @ W2^T + b2; distances + L2 ----------
__global__ __launch_bounds__(512, 1)
void gemm2_mfma(const unsigned short* __restrict__ h,
                const unsigned short* __restrict__ W2bf,
                const float* __restrict__ b2,
                float* __restrict__ pdp, float* __restrict__ pdn,
                float* __restrict__ pl2)
{
    __shared__ char smem[114688];
    char* const Ab = smem;            // 2 x 24576: A[par][mrow 192][k 64]
    char* const Bb = smem + 49152;    // 2 x 32768: B[par][col 256][k 64]

    const int lin = blockIdx.x;       // 2048 = 8 XCD * 256
    const int wgid = (lin & 7) * 256 + (lin >> 3);
    const int cb = wgid & 3;
    const int rb = wgid >> 2;         // 0..511
    const int tid  = threadIdx.x;
    const int lane = tid & 63, w = tid >> 6;
    const int wm = w >> 2, wn = w & 3;
    const int row0 = rb * 64;
    const int col0 = cb * 256;
    const int l15 = lane & 15, lq = lane >> 4;

    f32x4 acc[6][4] = {};             // [mh*3 + stream][nf]

    auto issueA = [&](int k0, char* Adst) {
        #pragma unroll
        for (int i = 0; i < 3; ++i) {
            const int f = i * 512 + tid;       // 0..1535
            const int mrow = f >> 3, c = f & 7;
            const int mf = mrow >> 4, rr = mrow & 15;
            const int ss = mf % 3, rf = mf / 3;
            gload16(&h[((size_t)ss * NROWS + row0 + rf * 16 + rr) * HIDD + k0 + ((c ^ (mrow & 7)) << 3)],
                    Adst + f * 16);
        }
    };
    auto issueB = [&](int k0, char* Bdst) {
        #pragma unroll
        for (int i = 0; i < 4; ++i) {
            const int f = i * 512 + tid;
            const int col = f >> 3, c = f & 7;
            gload16(&W2bf[(size_t)(col0 + col) * HIDD + k0 + ((c ^ (col & 7)) << 3)],
                    Bdst + f * 16);
        }
    };
    auto readA = [&](bf16x8 (&a)[3][2], int mh, char* Abase) {
        #pragma unroll
        for (int mm = 0; mm < 3; ++mm) {
            const int row = (wm * 6 + mh * 3 + mm) * 16 + l15;
            const int swz = (row & 7) << 4;
            #pragma unroll
            for (int ks = 0; ks < 2; ++ks)
                a[mm][ks] = *reinterpret_cast<const bf16x8*>(
                    Abase + ((row * 128 + ks * 64 + lq * 16) ^ swz));
        }
    };
    auto readB = [&](bf16x8 (&b)[2][2], int nh, char* Bbase) {
        #pragma unroll
        for (int nn = 0; nn < 2; ++nn) {
            const int col = wn * 64 + (nh * 2 + nn) * 16 + l15;
            const int swz = (col & 7) << 4;
            #pragma unroll
            for (int ks = 0; ks < 2; ++ks)
                b[nn][ks] = *reinterpret_cast<const bf16x8*>(
                    Bbase + ((col * 128 + ks * 64 + lq * 16) ^ swz));
        }
    };

    // ---- prologue ----
    issueA(0, Ab);
    MEMFENCE;
    issueB(0, Bb);
    WAIT_VM(0);
    BAR();

    for (int t = 0; t < 8; ++t) {
        char* const Apt = Ab + (t & 1) * 24576;
        char* const Apn = Ab + ((t & 1) ^ 1) * 24576;
        char* const Bpt = Bb + (t & 1) * 32768;
        char* const Bpn = Bb + ((t & 1) ^ 1) * 32768;
        const int kn = ((t < 7) ? (t + 1) : 7) * 64;

        bf16x8 a[3][2], b[2][2], a2[3][2];
        // ---- P1: (0,0); issue A(t+1)+B(t+1) ----
        readA(a, 0, Apt);
        readB(b, 0, Bpt);
        issueA(kn, Apn);
        MEMFENCE;
        issueB(kn, Bpn);
        BAR(); WAIT_LGKM0; SCHEDB(); SP1();
        #pragma unroll
        for (int mm = 0; mm < 3; ++mm)
            #pragma unroll
            for (int nn = 0; nn < 2; ++nn)
                #pragma unroll
                for (int ks = 0; ks < 2; ++ks)
                    acc[mm][nn] = MFMA16(a[mm][ks], b[nn][ks], acc[mm][nn]);
        SP0(); BAR();
        // ---- P2: (0,1) ----
        readB(b, 1, Bpt);
        BAR(); WAIT_LGKM0; SCHEDB(); SP1();
        #pragma unroll
        for (int mm = 0; mm < 3; ++mm)
            #pragma unroll
            for (int nn = 0; nn < 2; ++nn)
                #pragma unroll
                for (int ks = 0; ks < 2; ++ks)
                    acc[mm][2 + nn] = MFMA16(a[mm][ks], b[nn][ks], acc[mm][2 + nn]);
        SP0(); BAR();
        // ---- P3: (1,1) ----
        readA(a2, 1, Apt);
        BAR(); WAIT_LGKM0; SCHEDB(); SP1();
        #pragma unroll
        for (int mm = 0; mm < 3; ++mm)
            #pragma unroll
            for (int nn = 0; nn < 2; ++nn)
                #pragma unroll
                for (int ks = 0; ks < 2; ++ks)
                    acc[3 + mm][2 + nn] = MFMA16(a2[mm][ks], b[nn][ks], acc[3 + mm][2 + nn]);
        SP0(); BAR();
        // ---- P4: (1,0); drain prefetches (3 phases of cover) ----
        readB(b, 0, Bpt);
        WAIT_VM(0);
        BAR(); WAIT_LGKM0; SCHEDB(); SP1();
        #pragma unroll
        for (int mm = 0; mm < 3; ++mm)
            #pragma unroll
            for (int nn = 0; nn < 2; ++nn)
                #pragma unroll
                for (int ks = 0; ks < 2; ++ks)
                    acc[3 + mm][nn] = MFMA16(a2[mm][ks], b[nn][ks], acc[3 + mm][nn]);
        SP0(); BAR();
    }

    // epilogue: distances + L2 (stream = acc row % 3), never materializing e
    float b2c[4];
    #pragma unroll
    for (int nf = 0; nf < 4; ++nf) b2c[nf] = b2[col0 + wn * 64 + nf * 16 + l15];
    float l2t = 0.f;
    #pragma unroll
    for (int mh = 0; mh < 2; ++mh) {
        const int rbase = row0 + (wm * 2 + mh) * 16 + lq * 4;
        #pragma unroll
        for (int i = 0; i < 4; ++i) {
            float dp = 0.f, dn = 0.f;
            #pragma unroll
            for (int nf = 0; nf < 4; ++nf) {
                const float ea = acc[mh * 3 + 0][nf][i] + b2c[nf];
                const float ep = acc[mh * 3 + 1][nf][i] + b2c[nf];
                const float en = acc[mh * 3 + 2][nf][i] + b2c[nf];
                dp += (ea - ep) * (ea - ep);
                dn += (ea - en) * (ea - en);
                l2t += ea * ea + ep * ep + en * en;
            }
            #pragma unroll
            for (int mm = 1; mm < 16; mm <<= 1) {
                dp += __shfl_xor(dp, mm);
                dn += __shfl_xor(dn, mm);
            }
            if (l15 == 0) {
                pdp[(size_t)(cb * 4 + wn) * NROWS + rbase + i] = dp;
                pdn[(size_t)(cb * 4 + wn) * NROWS + rbase + i] = dn;
            }
        }
    }
    #pragma unroll
    for (int mm = 1; mm < 64; mm <<= 1) l2t += __shfl_xor(l2t, mm);
    __syncthreads();
    float* const l2red = (float*)smem;
    if (lane == 0) l2red[w] = l2t;
    __syncthreads();
    if (tid == 0) {
        float t = 0.f;
        #pragma unroll
        for (int ww = 0; ww < 8; ++ww) t += l2red[ww];
        pl2[wgid] = t;
    }
}

// ---------- per-row margins ----------
__global__ __launch_bounds__(256)
void margins_kernel(const float* __restrict__ pdp, const float* __restrict__ pdn,
                    float* __restrict__ margins, float* __restrict__ dd)
{
    const int r = blockIdx.x * 256 + threadIdx.x;
    float dp2 = 0.f, dn2 = 0.f;
    #pragma unroll
    for (int q = 0; q < 16; ++q) {
        dp2 += pdp[(size_t)q * NROWS + r];
        dn2 += pdn[(size_t)q * NROWS + r];
    }
    dd[r] = dn2 - dp2;
    margins[r] = (dn2 < dp2) ? (sqrtf(dp2) - sqrtf(dn2)) : 0.f;
}

// ---------- final: l2 sum + radix-select (parallel digit scan) + neighbor pass + loss ----------
__global__ __launch_bounds__(1024)
void final_kernel(const float* __restrict__ pl2, int npl2,
                  const float* __restrict__ margins, const float* __restrict__ dd,
                  float* __restrict__ out)
{
    __shared__ unsigned hist[256];
    __shared__ float warp_red[16];
    __shared__ unsigned wsum[4];
    __shared__ unsigned sh_prefix;
    __shared__ int sh_k;
    __shared__ float sh_l2;
    __shared__ unsigned sh_cle;
    __shared__ unsigned sh_minAbove;
    const int tid = threadIdx.x;

    float l2 = 0.f;
    for (int i = tid; i < npl2; i += 1024) l2 += pl2[i];
    #pragma unroll
    for (int m = 1; m < 64; m <<= 1) l2 += __shfl_xor(l2, m);
    if ((tid & 63) == 0) warp_red[tid >> 6] = l2;
    __syncthreads();
    if (tid == 0) {
        float t = 0.f;
        for (int w = 0; w < 16; ++w) t += warp_red[w];
        sh_l2 = t;
        sh_k = 8191; sh_prefix = 0u;
        sh_cle = 0u; sh_minAbove = 0xFFFFFFFFu;
    }
    __syncthreads();

    for (int shift = 24; shift >= 0; shift -= 8) {
        if (tid < 256) hist[tid] = 0u;
        __syncthreads();
        const unsigned prefix = sh_prefix;
        const int kcur = sh_k;
        const unsigned mask = (shift == 24) ? 0u : (0xFFFFFFFFu << (shift + 8));
        for (int i = tid; i < NROWS; i += 1024) {
            const unsigned key = __float_as_uint(margins[i]);
            if (((key ^ prefix) & mask) == 0u)
                atomicAdd(&hist[(key >> shift) & 255u], 1u);
        }
        __syncthreads();
        unsigned v = 0, cme = 0;
        if (tid < 256) {
            cme = hist[tid];
            v = cme;
            #pragma unroll
            for (int off = 1; off < 64; off <<= 1) {
                unsigned tt = __shfl_up(v, off);
                if ((tid & 63) >= off) v += tt;
            }
            if ((tid & 63) == 63) wsum[tid >> 6] = v;
        }
        __syncthreads();
        if (tid < 256) {
            unsigned wo = 0;
            for (int i = 0; i < (tid >> 6); ++i) wo += wsum[i];
            const unsigned incl = v + wo;
            const unsigned excl = incl - cme;
            if ((unsigned)kcur >= excl && (unsigned)kcur < incl) {
                sh_prefix = prefix | ((unsigned)tid << shift);
                sh_k = kcur - (int)excl;
            }
        }
        __syncthreads();
    }
    const unsigned p1u = sh_prefix;

    unsigned lc = 0, lmin = 0xFFFFFFFFu;
    for (int i = tid; i < NROWS; i += 1024) {
        const unsigned key = __float_as_uint(margins[i]);
        if (key <= p1u) ++lc; else lmin = min(lmin, key);
    }
    #pragma unroll
    for (int m = 1; m < 64; m <<= 1) {
        lc += __shfl_xor(lc, m);
        lmin = min(lmin, (unsigned)__shfl_xor((int)lmin, m));
    }
    if ((tid & 63) == 0) {
        atomicAdd(&sh_cle, lc);
        atomicMin(&sh_minAbove, lmin);
    }
    __syncthreads();
    const float p1 = __uint_as_float(p1u);
    const float p2 = (sh_cle >= 8193u) ? p1 : __uint_as_float(sh_minAbove);
    const float margin = p1 + 0.75f * (p2 - p1);

    float ssum = 0.f;
    for (int i = tid; i < NROWS; i += 1024) {
        const float t = dd[i] + margin;
        ssum += (t > 0.f) ? t : 0.f;
    }
    #pragma unroll
    for (int m = 1; m < 64; m <<= 1) ssum += __shfl_xor(ssum, m);
    if ((tid & 63) == 0) warp_red[tid >> 6] = ssum;
    __syncthreads();
    if (tid == 0) {
        float S = 0.f;
        for (int w = 0; w < 16; ++w) S += warp_red[w];
        out[0] = S / (float)NROWS + 1e-3f * sh_l2 / (float)NROWS;
    }
}

extern "C" void kernel_launch(void* const* d_in, const int* in_sizes, int n_in,
                              void* d_out, int out_size, void* d_ws, size_t ws_size,
                              hipStream_t stream) {
    (void)in_sizes; (void)n_in; (void)out_size; (void)ws_size;
    const float* item = (const float*)d_in[0];
    const float* pos  = (const float*)d_in[1];
    const float* neg  = (const float*)d_in[2];
    const float* W1   = (const float*)d_in[3];
    const float* b1   = (const float*)d_in[4];
    const float* gam  = (const float*)d_in[5];
    const float* bet  = (const float*)d_in[6];
    const float* rmu  = (const float*)d_in[7];
    const float* rvr  = (const float*)d_in[8];
    const float* W2   = (const float*)d_in[9];
    const float* b2   = (const float*)d_in[10];

    char* ws = (char*)d_ws;
    unsigned short* h = (unsigned short*)ws;
    size_t off = (size_t)M3 * HIDD * sizeof(unsigned short);
    unsigned short* W1bf = (unsigned short*)(ws + off); off += (size_t)HIDD * DIM * 2;
    unsigned short* W2bf = (unsigned short*)(ws + off); off += (size_t)DIM * HIDD * 2;
    float* pdp = (float*)(ws + off); off += (size_t)16 * NROWS * 4;
    float* pdn = (float*)(ws + off); off += (size_t)16 * NROWS * 4;
    float* pl2 = (float*)(ws + off); off += (size_t)2048 * 4;
    float* margins = (float*)(ws + off); off += (size_t)NROWS * 4;
    float* dd = (float*)(ws + off); off += (size_t)NROWS * 4;

    cvt_kernel<<<dim3((HIDD*DIM/4 + 255)/256), 256, 0, stream>>>(W1, W1bf, HIDD*DIM/4);
    cvt_kernel<<<dim3((DIM*HIDD/4 + 255)/256), 256, 0, stream>>>(W2, W2bf, DIM*HIDD/4);
    gemm1_mfma<<<dim3(3072), 256, 0, stream>>>(
        item, pos, neg, W1bf, b1, gam, bet, rmu, rvr, h);
    gemm2_mfma<<<dim3(2048), 512, 0, stream>>>(
        h, W2bf, b2, pdp, pdn, pl2);
    margins_kernel<<<dim3(NROWS/256), 256, 0, stream>>>(pdp, pdn, margins, dd);
    final_kernel<<<1, 1024, 0, stream>>>(pl2, 2048, margins, dd, (float*)d_out);
}

// Round 13
// 421.553 us; speedup vs baseline: 1.1345x; 1.0446x over previous
//
#include <hip/hip_runtime.h>

#define NROWS 32768
#define DIM   1024
#define HIDD  512
#define M3    (3*NROWS)

using bf16x8 = __attribute__((ext_vector_type(8))) short;
using f32x4  = __attribute__((ext_vector_type(4))) float;

#define MFMA16(a,b,c) __builtin_amdgcn_mfma_f32_16x16x32_bf16(a,b,c,0,0,0)
#define WAIT_VM(N)  asm volatile("s_waitcnt vmcnt(" #N ")" ::: "memory")
#define WAIT_LGKM0  asm volatile("s_waitcnt lgkmcnt(0)" ::: "memory")
#define MEMFENCE    asm volatile("" ::: "memory")
#define BAR()       __builtin_amdgcn_s_barrier()
#define SCHEDB()    __builtin_amdgcn_sched_barrier(0)
#define SP1()       __builtin_amdgcn_s_setprio(1)
#define SP0()       __builtin_amdgcn_s_setprio(0)

// ---------- helpers ----------
static __device__ __forceinline__ unsigned short f2bf(float f) {
    unsigned u = __float_as_uint(f);
    u += 0x7FFFu + ((u >> 16) & 1u);   // round-to-nearest-even
    return (unsigned short)(u >> 16);
}
static __device__ __forceinline__ unsigned cvtpk(float a, float b) {
    unsigned r;
    asm("v_cvt_pk_bf16_f32 %0, %1, %2" : "=v"(r) : "v"(a), "v"(b));
    return r;
}
static __device__ __forceinline__ void gload16(const void* gsrc, void* ldst) {
    __builtin_amdgcn_global_load_lds(
        (const __attribute__((address_space(1))) unsigned int*)gsrc,
        (__attribute__((address_space(3))) unsigned int*)ldst,
        16, 0, 0);
}

// ---------- convert fp32 -> bf16, W1 and W2 in one launch ----------
__global__ __launch_bounds__(256)
void cvt2_kernel(const float* __restrict__ src1, unsigned short* __restrict__ dst1,
                 const float* __restrict__ src2, unsigned short* __restrict__ dst2,
                 int n4each)
{
    const int i = blockIdx.x * 256 + threadIdx.x;
    const float* src = (i < n4each) ? src1 : src2;
    unsigned short* dst = (i < n4each) ? dst1 : dst2;
    const int j = (i < n4each) ? i : (i - n4each);
    if (j < n4each) {
        float4 v = reinterpret_cast<const float4*>(src)[j];
        uint2 o;
        o.x = cvtpk(v.x, v.y);
        o.y = cvtpk(v.z, v.w);
        reinterpret_cast<uint2*>(dst)[j] = o;
    }
}

// ---------- GEMM1 (R3/R9-verified structure): h = leaky(bn(x @ W1^T + b1)) ----------
// 3072 blocks, XCD-swizzled. 128x128 tile, BK=64, 4 waves each own 64x64 (4x4 frags).
// Order per K-tile: stage A (cvt from regs) -> issue B gload16 -> __syncthreads ->
// issue next aR -> frags+MFMA -> __syncthreads. (Best measured: ~250 us.)
__global__ __launch_bounds__(256)
void gemm1_mfma(const float* __restrict__ x0, const float* __restrict__ x1,
                const float* __restrict__ x2,
                const unsigned short* __restrict__ W1bf,
                const float* __restrict__ b1, const float* __restrict__ gamma,
                const float* __restrict__ beta, const float* __restrict__ rmean,
                const float* __restrict__ rvar,
                unsigned short* __restrict__ h)
{
    __shared__ unsigned short Abuf[128*64];      // [r][64], byte ^((r&7)<<4)
    __shared__ unsigned short Bbuf[2*128*32];    // [panel][col][32], chunk-permuted

    const int lin = blockIdx.x;                  // 3072 = 8 XCD * 384
    const int wgid = (lin & 7) * 384 + (lin >> 3);
    const int cb = wgid & 3;
    const int rb = wgid >> 2;
    const int tid  = threadIdx.x;
    const int lane = tid & 63, w = tid >> 6;
    const int wr = w >> 1, wc = w & 1;
    const int row0 = rb * 128;
    const int s = row0 >> 15;
    const float* x = (s == 0) ? x0 : (s == 1 ? x1 : x2);
    const int rl0 = row0 & (NROWS - 1);
    const int col0 = cb * 128;
    const int l15 = lane & 15, lq = lane >> 4;

    f32x4 acc[4][4] = {};
    float4 aR[8];

    #pragma unroll
    for (int p = 0; p < 8; ++p) {
        const int f = p * 256 + tid;
        const int r = f >> 4, c4 = f & 15;
        aR[p] = *reinterpret_cast<const float4*>(&x[(size_t)(rl0 + r) * DIM + c4 * 4]);
    }

    for (int t = 0; t < 16; ++t) {
        const int k0 = t * 64;
        // ---- stage A (cvt from regs, XOR-swizzled) ----
        #pragma unroll
        for (int p = 0; p < 8; ++p) {
            const int f = p * 256 + tid;
            const int r = f >> 4, c4 = f & 15;
            const unsigned off = (unsigned)((r * 128 + c4 * 8) ^ ((r & 7) << 4));
            uint2 o;
            o.x = cvtpk(aR[p].x, aR[p].y);
            o.y = cvtpk(aR[p].z, aR[p].w);
            *reinterpret_cast<uint2*>(reinterpret_cast<char*>(Abuf) + off) = o;
        }
        // ---- stage B via global_load_lds (source chunk-permuted) ----
        #pragma unroll
        for (int c = 0; c < 4; ++c) {
            const int f = c * 256 + tid;
            const int panel = f >> 9;
            const int cc = (f >> 2) & 127;
            const int chunk = (f & 3) ^ ((cc >> 1) & 3);
            gload16(&W1bf[(size_t)(col0 + cc) * DIM + k0 + panel * 32 + chunk * 8],
                    reinterpret_cast<char*>(Bbuf) + (size_t)f * 16);
        }
        __syncthreads();
        // ---- issue next A loads (drain hidden under MFMA at next barrier) ----
        if (t < 15) {
            #pragma unroll
            for (int p = 0; p < 8; ++p) {
                const int f = p * 256 + tid;
                const int r = f >> 4, c4 = f & 15;
                aR[p] = *reinterpret_cast<const float4*>(
                    &x[(size_t)(rl0 + r) * DIM + k0 + 64 + c4 * 4]);
            }
        }
        // ---- fragments + MFMA ----
        bf16x8 bfv[2][4];
        #pragma unroll
        for (int kk = 0; kk < 2; ++kk)
            #pragma unroll
            for (int n = 0; n < 4; ++n) {
                const int colr = wc*64 + n*16 + l15;
                const int slq = lq ^ ((colr >> 1) & 3);
                bfv[kk][n] = *reinterpret_cast<const bf16x8*>(
                    reinterpret_cast<char*>(Bbuf) + kk*8192 + colr*64 + slq*16);
            }
        #pragma unroll
        for (int kk = 0; kk < 2; ++kk)
            #pragma unroll
            for (int m = 0; m < 4; ++m) {
                const int row = wr*64 + m*16 + l15;
                const unsigned ab = (unsigned)((row*128 + kk*64 + lq*16) ^ ((row & 7) << 4));
                bf16x8 af = *reinterpret_cast<const bf16x8*>(
                    reinterpret_cast<char*>(Abuf) + ab);
                #pragma unroll
                for (int n = 0; n < 4; ++n)
                    acc[m][n] = MFMA16(af, bfv[kk][n], acc[m][n]);
            }
        __syncthreads();
    }

    // epilogue: BN(eval) + leaky folded to v*A + B per column
    float As[4], Bsc[4];
    #pragma unroll
    for (int n = 0; n < 4; ++n) {
        const int c = col0 + wc*64 + n*16 + l15;
        const float inv = rsqrtf(rvar[c] + 1e-5f);
        As[n]  = inv * gamma[c];
        Bsc[n] = (b1[c] - rmean[c]) * As[n] + beta[c];
    }
    #pragma unroll
    for (int m = 0; m < 4; ++m) {
        const int rbase = row0 + wr*64 + m*16 + lq*4;
        #pragma unroll
        for (int n = 0; n < 4; ++n) {
            const int c = col0 + wc*64 + n*16 + l15;
            #pragma unroll
            for (int i = 0; i < 4; ++i) {
                float v = fmaf(acc[m][n][i], As[n], Bsc[n]);
                v = (v >= 0.f) ? v : 0.1f * v;
                h[(size_t)(rbase + i) * HIDD + c] = f2bf(v);
            }
        }
    }
}

// ---------- GEMM2 (8-phase fused, best-measured): e = h @ W2^T + b2; distances + L2 ----------
__global__ __launch_bounds__(512, 1)
void gemm2_mfma(const unsigned short* __restrict__ h,
                const unsigned short* __restrict__ W2bf,
                const float* __restrict__ b2,
                float* __restrict__ pdp, float* __restrict__ pdn,
                float* __restrict__ pl2)
{
    __shared__ char smem[114688];
    char* const Ab = smem;            // 2 x 24576: A[par][mrow 192][k 64]
    char* const Bb = smem + 49152;    // 2 x 32768: B[par][col 256][k 64]

    const int lin = blockIdx.x;       // 2048 = 8 XCD * 256
    const int wgid = (lin & 7) * 256 + (lin >> 3);
    const int cb = wgid & 3;
    const int rb = wgid >> 2;         // 0..511
    const int tid  = threadIdx.x;
    const int lane = tid & 63, w = tid >> 6;
    const int wm = w >> 2, wn = w & 3;
    const int row0 = rb * 64;
    const int col0 = cb * 256;
    const int l15 = lane & 15, lq = lane >> 4;

    f32x4 acc[6][4] = {};             // [mh*3 + stream][nf]

    auto issueA = [&](int k0, char* Adst) {
        #pragma unroll
        for (int i = 0; i < 3; ++i) {
            const int f = i * 512 + tid;       // 0..1535
            const int mrow = f >> 3, c = f & 7;
            const int mf = mrow >> 4, rr = mrow & 15;
            const int ss = mf % 3, rf = mf / 3;
            gload16(&h[((size_t)ss * NROWS + row0 + rf * 16 + rr) * HIDD + k0 + ((c ^ (mrow & 7)) << 3)],
                    Adst + f * 16);
        }
    };
    auto issueB = [&](int k0, char* Bdst) {
        #pragma unroll
        for (int i = 0; i < 4; ++i) {
            const int f = i * 512 + tid;
            const int col = f >> 3, c = f & 7;
            gload16(&W2bf[(size_t)(col0 + col) * HIDD + k0 + ((c ^ (col & 7)) << 3)],
                    Bdst + f * 16);
        }
    };
    auto readA = [&](bf16x8 (&a)[3][2], int mh, char* Abase) {
        #pragma unroll
        for (int mm = 0; mm < 3; ++mm) {
            const int row = (wm * 6 + mh * 3 + mm) * 16 + l15;
            const int swz = (row & 7) << 4;
            #pragma unroll
            for (int ks = 0; ks < 2; ++ks)
                a[mm][ks] = *reinterpret_cast<const bf16x8*>(
                    Abase + ((row * 128 + ks * 64 + lq * 16) ^ swz));
        }
    };
    auto readB = [&](bf16x8 (&b)[2][2], int nh, char* Bbase) {
        #pragma unroll
        for (int nn = 0; nn < 2; ++nn) {
            const int col = wn * 64 + (nh * 2 + nn) * 16 + l15;
            const int swz = (col & 7) << 4;
            #pragma unroll
            for (int ks = 0; ks < 2; ++ks)
                b[nn][ks] = *reinterpret_cast<const bf16x8*>(
                    Bbase + ((col * 128 + ks * 64 + lq * 16) ^ swz));
        }
    };

    // ---- prologue ----
    issueA(0, Ab);
    MEMFENCE;
    issueB(0, Bb);
    WAIT_VM(0);
    BAR();

    for (int t = 0; t < 8; ++t) {
        char* const Apt = Ab + (t & 1) * 24576;
        char* const Apn = Ab + ((t & 1) ^ 1) * 24576;
        char* const Bpt = Bb + (t & 1) * 32768;
        char* const Bpn = Bb + ((t & 1) ^ 1) * 32768;
        const int kn = ((t < 7) ? (t + 1) : 7) * 64;

        bf16x8 a[3][2], b[2][2], a2[3][2];
        // ---- P1: (0,0); issue A(t+1)+B(t+1) ----
        readA(a, 0, Apt);
        readB(b, 0, Bpt);
        issueA(kn, Apn);
        MEMFENCE;
        issueB(kn, Bpn);
        BAR(); WAIT_LGKM0; SCHEDB(); SP1();
        #pragma unroll
        for (int mm = 0; mm < 3; ++mm)
            #pragma unroll
            for (int nn = 0; nn < 2; ++nn)
                #pragma unroll
                for (int ks = 0; ks < 2; ++ks)
                    acc[mm][nn] = MFMA16(a[mm][ks], b[nn][ks], acc[mm][nn]);
        SP0(); BAR();
        // ---- P2: (0,1) ----
        readB(b, 1, Bpt);
        BAR(); WAIT_LGKM0; SCHEDB(); SP1();
        #pragma unroll
        for (int mm = 0; mm < 3; ++mm)
            #pragma unroll
            for (int nn = 0; nn < 2; ++nn)
                #pragma unroll
                for (int ks = 0; ks < 2; ++ks)
                    acc[mm][2 + nn] = MFMA16(a[mm][ks], b[nn][ks], acc[mm][2 + nn]);
        SP0(); BAR();
        // ---- P3: (1,1) ----
        readA(a2, 1, Apt);
        BAR(); WAIT_LGKM0; SCHEDB(); SP1();
        #pragma unroll
        for (int mm = 0; mm < 3; ++mm)
            #pragma unroll
            for (int nn = 0; nn < 2; ++nn)
                #pragma unroll
                for (int ks = 0; ks < 2; ++ks)
                    acc[3 + mm][2 + nn] = MFMA16(a2[mm][ks], b[nn][ks], acc[3 + mm][2 + nn]);
        SP0(); BAR();
        // ---- P4: (1,0); drain prefetches (3 phases of cover) ----
        readB(b, 0, Bpt);
        WAIT_VM(0);
        BAR(); WAIT_LGKM0; SCHEDB(); SP1();
        #pragma unroll
        for (int mm = 0; mm < 3; ++mm)
            #pragma unroll
            for (int nn = 0; nn < 2; ++nn)
                #pragma unroll
                for (int ks = 0; ks < 2; ++ks)
                    acc[3 + mm][nn] = MFMA16(a2[mm][ks], b[nn][ks], acc[3 + mm][nn]);
        SP0(); BAR();
    }

    // epilogue: distances + L2 (stream = acc row % 3), never materializing e
    float b2c[4];
    #pragma unroll
    for (int nf = 0; nf < 4; ++nf) b2c[nf] = b2[col0 + wn * 64 + nf * 16 + l15];
    float l2t = 0.f;
    #pragma unroll
    for (int mh = 0; mh < 2; ++mh) {
        const int rbase = row0 + (wm * 2 + mh) * 16 + lq * 4;
        #pragma unroll
        for (int i = 0; i < 4; ++i) {
            float dp = 0.f, dn = 0.f;
            #pragma unroll
            for (int nf = 0; nf < 4; ++nf) {
                const float ea = acc[mh * 3 + 0][nf][i] + b2c[nf];
                const float ep = acc[mh * 3 + 1][nf][i] + b2c[nf];
                const float en = acc[mh * 3 + 2][nf][i] + b2c[nf];
                dp += (ea - ep) * (ea - ep);
                dn += (ea - en) * (ea - en);
                l2t += ea * ea + ep * ep + en * en;
            }
            #pragma unroll
            for (int mm = 1; mm < 16; mm <<= 1) {
                dp += __shfl_xor(dp, mm);
                dn += __shfl_xor(dn, mm);
            }
            if (l15 == 0) {
                pdp[(size_t)(cb * 4 + wn) * NROWS + rbase + i] = dp;
                pdn[(size_t)(cb * 4 + wn) * NROWS + rbase + i] = dn;
            }
        }
    }
    #pragma unroll
    for (int mm = 1; mm < 64; mm <<= 1) l2t += __shfl_xor(l2t, mm);
    __syncthreads();
    float* const l2red = (float*)smem;
    if (lane == 0) l2red[w] = l2t;
    __syncthreads();
    if (tid == 0) {
        float t = 0.f;
        #pragma unroll
        for (int ww = 0; ww < 8; ++ww) t += l2red[ww];
        pl2[wgid] = t;
    }
}

// ---------- per-row margins ----------
__global__ __launch_bounds__(256)
void margins_kernel(const float* __restrict__ pdp, const float* __restrict__ pdn,
                    float* __restrict__ margins, float* __restrict__ dd)
{
    const int r = blockIdx.x * 256 + threadIdx.x;
    float dp2 = 0.f, dn2 = 0.f;
    #pragma unroll
    for (int q = 0; q < 16; ++q) {
        dp2 += pdp[(size_t)q * NROWS + r];
        dn2 += pdn[(size_t)q * NROWS + r];
    }
    dd[r] = dn2 - dp2;
    margins[r] = (dn2 < dp2) ? (sqrtf(dp2) - sqrtf(dn2)) : 0.f;
}

// ---------- final: l2 sum + radix-select (parallel digit scan) + neighbor pass + loss ----------
__global__ __launch_bounds__(1024)
void final_kernel(const float* __restrict__ pl2, int npl2,
                  const float* __restrict__ margins, const float* __restrict__ dd,
                  float* __restrict__ out)
{
    __shared__ unsigned hist[256];
    __shared__ float warp_red[16];
    __shared__ unsigned wsum[4];
    __shared__ unsigned sh_prefix;
    __shared__ int sh_k;
    __shared__ float sh_l2;
    __shared__ unsigned sh_cle;
    __shared__ unsigned sh_minAbove;
    const int tid = threadIdx.x;

    float l2 = 0.f;
    for (int i = tid; i < npl2; i += 1024) l2 += pl2[i];
    #pragma unroll
    for (int m = 1; m < 64; m <<= 1) l2 += __shfl_xor(l2, m);
    if ((tid & 63) == 0) warp_red[tid >> 6] = l2;
    __syncthreads();
    if (tid == 0) {
        float t = 0.f;
        for (int w = 0; w < 16; ++w) t += warp_red[w];
        sh_l2 = t;
        sh_k = 8191; sh_prefix = 0u;
        sh_cle = 0u; sh_minAbove = 0xFFFFFFFFu;
    }
    __syncthreads();

    for (int shift = 24; shift >= 0; shift -= 8) {
        if (tid < 256) hist[tid] = 0u;
        __syncthreads();
        const unsigned prefix = sh_prefix;
        const int kcur = sh_k;
        const unsigned mask = (shift == 24) ? 0u : (0xFFFFFFFFu << (shift + 8));
        for (int i = tid; i < NROWS; i += 1024) {
            const unsigned key = __float_as_uint(margins[i]);
            if (((key ^ prefix) & mask) == 0u)
                atomicAdd(&hist[(key >> shift) & 255u], 1u);
        }
        __syncthreads();
        unsigned v = 0, cme = 0;
        if (tid < 256) {
            cme = hist[tid];
            v = cme;
            #pragma unroll
            for (int off = 1; off < 64; off <<= 1) {
                unsigned tt = __shfl_up(v, off);
                if ((tid & 63) >= off) v += tt;
            }
            if ((tid & 63) == 63) wsum[tid >> 6] = v;
        }
        __syncthreads();
        if (tid < 256) {
            unsigned wo = 0;
            for (int i = 0; i < (tid >> 6); ++i) wo += wsum[i];
            const unsigned incl = v + wo;
            const unsigned excl = incl - cme;
            if ((unsigned)kcur >= excl && (unsigned)kcur < incl) {
                sh_prefix = prefix | ((unsigned)tid << shift);
                sh_k = kcur - (int)excl;
            }
        }
        __syncthreads();
    }
    const unsigned p1u = sh_prefix;

    unsigned lc = 0, lmin = 0xFFFFFFFFu;
    for (int i = tid; i < NROWS; i += 1024) {
        const unsigned key = __float_as_uint(margins[i]);
        if (key <= p1u) ++lc; else lmin = min(lmin, key);
    }
    #pragma unroll
    for (int m = 1; m < 64; m <<= 1) {
        lc += __shfl_xor(lc, m);
        lmin = min(lmin, (unsigned)__shfl_xor((int)lmin, m));
    }
    if ((tid & 63) == 0) {
        atomicAdd(&sh_cle, lc);
        atomicMin(&sh_minAbove, lmin);
    }
    __syncthreads();
    const float p1 = __uint_as_float(p1u);
    const float p2 = (sh_cle >= 8193u) ? p1 : __uint_as_float(sh_minAbove);
    const float margin = p1 + 0.75f * (p2 - p1);

    float ssum = 0.f;
    for (int i = tid; i < NROWS; i += 1024) {
        const float t = dd[i] + margin;
        ssum += (t > 0.f) ? t : 0.f;
    }
    #pragma unroll
    for (int m = 1; m < 64; m <<= 1) ssum += __shfl_xor(ssum, m);
    if ((tid & 63) == 0) warp_red[tid >> 6] = ssum;
    __syncthreads();
    if (tid == 0) {
        float S = 0.f;
        for (int w = 0; w < 16; ++w) S += warp_red[w];
        out[0] = S / (float)NROWS + 1e-3f * sh_l2 / (float)NROWS;
    }
}

extern "C" void kernel_launch(void* const* d_in, const int* in_sizes, int n_in,
                              void* d_out, int out_size, void* d_ws, size_t ws_size,
                              hipStream_t stream) {
    (void)in_sizes; (void)n_in; (void)out_size; (void)ws_size;
    const float* item = (const float*)d_in[0];
    const float* pos  = (const float*)d_in[1];
    const float* neg  = (const float*)d_in[2];
    const float* W1   = (const float*)d_in[3];
    const float* b1   = (const float*)d_in[4];
    const float* gam  = (const float*)d_in[5];
    const float* bet  = (const float*)d_in[6];
    const float* rmu  = (const float*)d_in[7];
    const float* rvr  = (const float*)d_in[8];
    const float* W2   = (const float*)d_in[9];
    const float* b2   = (const float*)d_in[10];

    char* ws = (char*)d_ws;
    unsigned short* h = (unsigned short*)ws;
    size_t off = (size_t)M3 * HIDD * sizeof(unsigned short);
    unsigned short* W1bf = (unsigned short*)(ws + off); off += (size_t)HIDD * DIM * 2;
    unsigned short* W2bf = (unsigned short*)(ws + off); off += (size_t)DIM * HIDD * 2;
    float* pdp = (float*)(ws + off); off += (size_t)16 * NROWS * 4;
    float* pdn = (float*)(ws + off); off += (size_t)16 * NROWS * 4;
    float* pl2 = (float*)(ws + off); off += (size_t)2048 * 4;
    float* margins = (float*)(ws + off); off += (size_t)NROWS * 4;
    float* dd = (float*)(ws + off); off += (size_t)NROWS * 4;

    const int n4each = HIDD * DIM / 4;           // 131072 float4s per weight
    cvt2_kernel<<<dim3(2 * n4each / 256), 256, 0, stream>>>(W1, W1bf, W2, W2bf, n4each);
    gemm1_mfma<<<dim3(3072), 256, 0, stream>>>(
        item, pos, neg, W1bf, b1, gam, bet, rmu, rvr, h);
    gemm2_mfma<<<dim3(2048), 512, 0, stream>>>(
        h, W2bf, b2, pdp, pdn, pl2);
    margins_kernel<<<dim3(NROWS/256), 256, 0, stream>>>(pdp, pdn, margins, dd);
    final_kernel<<<1, 1024, 0, stream>>>(pl2, 2048, margins, dd, (float*)d_out);
}

// Round 14
// 408.792 us; speedup vs baseline: 1.1699x; 1.0312x over previous
//
#include <hip/hip_runtime.h>

#define NROWS 32768
#define DIM   1024
#define HIDD  512
#define M3    (3*NROWS)

using bf16x8 = __attribute__((ext_vector_type(8))) short;
using f32x4  = __attribute__((ext_vector_type(4))) float;

#define MFMA16(a,b,c) __builtin_amdgcn_mfma_f32_16x16x32_bf16(a,b,c,0,0,0)
#define WAIT_VM(N)  asm volatile("s_waitcnt vmcnt(" #N ")" ::: "memory")
#define WAIT_LGKM0  asm volatile("s_waitcnt lgkmcnt(0)" ::: "memory")
#define MEMFENCE    asm volatile("" ::: "memory")
#define BAR()       __builtin_amdgcn_s_barrier()
#define SCHEDB()    __builtin_amdgcn_sched_barrier(0)
#define SP1()       __builtin_amdgcn_s_setprio(1)
#define SP0()       __builtin_amdgcn_s_setprio(0)

// ---------- helpers ----------
static __device__ __forceinline__ unsigned short f2bf(float f) {
    unsigned u = __float_as_uint(f);
    u += 0x7FFFu + ((u >> 16) & 1u);   // round-to-nearest-even
    return (unsigned short)(u >> 16);
}
static __device__ __forceinline__ unsigned cvtpk(float a, float b) {
    unsigned r;
    asm("v_cvt_pk_bf16_f32 %0, %1, %2" : "=v"(r) : "v"(a), "v"(b));
    return r;
}
static __device__ __forceinline__ void gload16(const void* gsrc, void* ldst) {
    __builtin_amdgcn_global_load_lds(
        (const __attribute__((address_space(1))) unsigned int*)gsrc,
        (__attribute__((address_space(3))) unsigned int*)ldst,
        16, 0, 0);
}

// ---------- convert fp32 -> bf16, W1 and W2 in one launch ----------
__global__ __launch_bounds__(256)
void cvt2_kernel(const float* __restrict__ src1, unsigned short* __restrict__ dst1,
                 const float* __restrict__ src2, unsigned short* __restrict__ dst2,
                 int n4each)
{
    const int i = blockIdx.x * 256 + threadIdx.x;
    const float* src = (i < n4each) ? src1 : src2;
    unsigned short* dst = (i < n4each) ? dst1 : dst2;
    const int j = (i < n4each) ? i : (i - n4each);
    if (j < n4each) {
        float4 v = reinterpret_cast<const float4*>(src)[j];
        uint2 o;
        o.x = cvtpk(v.x, v.y);
        o.y = cvtpk(v.z, v.w);
        reinterpret_cast<uint2*>(dst)[j] = o;
    }
}

// ---------- GEMM1 v13: R13 tile/schedule, 512 threads / 8 waves (occupancy lever) ----------
// Same 128x128 tile, BK=64, same swizzles, same 2-barrier order. Each wave owns 64x32
// (4x2 frags). Per-thread resources halve (acc 8 f32x4, aR 4, 4 A-stage + 2 B-gload)
// so more blocks/CU co-reside and overlap each other's barrier drains (m114 mechanism).
__global__ __launch_bounds__(512)
void gemm1_mfma(const float* __restrict__ x0, const float* __restrict__ x1,
                const float* __restrict__ x2,
                const unsigned short* __restrict__ W1bf,
                const float* __restrict__ b1, const float* __restrict__ gamma,
                const float* __restrict__ beta, const float* __restrict__ rmean,
                const float* __restrict__ rvar,
                unsigned short* __restrict__ h)
{
    __shared__ unsigned short Abuf[128*64];      // [r][64], byte ^((r&7)<<4)
    __shared__ unsigned short Bbuf[2*128*32];    // [panel][col][32], chunk-permuted

    const int lin = blockIdx.x;                  // 3072 = 8 XCD * 384
    const int wgid = (lin & 7) * 384 + (lin >> 3);
    const int cb = wgid & 3;
    const int rb = wgid >> 2;
    const int tid  = threadIdx.x;                // 0..511
    const int lane = tid & 63, w = tid >> 6;     // 8 waves
    const int wr = w >> 2, wc = w & 3;           // 2 x 4 wave grid
    const int row0 = rb * 128;
    const int s = row0 >> 15;
    const float* x = (s == 0) ? x0 : (s == 1 ? x1 : x2);
    const int rl0 = row0 & (NROWS - 1);
    const int col0 = cb * 128;
    const int l15 = lane & 15, lq = lane >> 4;

    f32x4 acc[4][2] = {};                        // [m][n]
    float4 aR[4];

    #pragma unroll
    for (int p = 0; p < 4; ++p) {
        const int f = p * 512 + tid;             // 0..2047
        const int r = f >> 4, c4 = f & 15;
        aR[p] = *reinterpret_cast<const float4*>(&x[(size_t)(rl0 + r) * DIM + c4 * 4]);
    }

    for (int t = 0; t < 16; ++t) {
        const int k0 = t * 64;
        // ---- stage A (cvt from regs, XOR-swizzled) ----
        #pragma unroll
        for (int p = 0; p < 4; ++p) {
            const int f = p * 512 + tid;
            const int r = f >> 4, c4 = f & 15;
            const unsigned off = (unsigned)((r * 128 + c4 * 8) ^ ((r & 7) << 4));
            uint2 o;
            o.x = cvtpk(aR[p].x, aR[p].y);
            o.y = cvtpk(aR[p].z, aR[p].w);
            *reinterpret_cast<uint2*>(reinterpret_cast<char*>(Abuf) + off) = o;
        }
        // ---- stage B via global_load_lds (source chunk-permuted) ----
        #pragma unroll
        for (int c = 0; c < 2; ++c) {
            const int f = c * 512 + tid;         // 0..1023
            const int panel = f >> 9;
            const int cc = (f >> 2) & 127;
            const int chunk = (f & 3) ^ ((cc >> 1) & 3);
            gload16(&W1bf[(size_t)(col0 + cc) * DIM + k0 + panel * 32 + chunk * 8],
                    reinterpret_cast<char*>(Bbuf) + (size_t)f * 16);
        }
        __syncthreads();
        // ---- issue next A loads (drain hidden under MFMA at next barrier) ----
        if (t < 15) {
            #pragma unroll
            for (int p = 0; p < 4; ++p) {
                const int f = p * 512 + tid;
                const int r = f >> 4, c4 = f & 15;
                aR[p] = *reinterpret_cast<const float4*>(
                    &x[(size_t)(rl0 + r) * DIM + k0 + 64 + c4 * 4]);
            }
        }
        // ---- fragments + MFMA ----
        bf16x8 bfv[2][2];
        #pragma unroll
        for (int kk = 0; kk < 2; ++kk)
            #pragma unroll
            for (int n = 0; n < 2; ++n) {
                const int colr = wc*32 + n*16 + l15;
                const int slq = lq ^ ((colr >> 1) & 3);
                bfv[kk][n] = *reinterpret_cast<const bf16x8*>(
                    reinterpret_cast<char*>(Bbuf) + kk*8192 + colr*64 + slq*16);
            }
        #pragma unroll
        for (int kk = 0; kk < 2; ++kk)
            #pragma unroll
            for (int m = 0; m < 4; ++m) {
                const int row = wr*64 + m*16 + l15;
                const unsigned ab = (unsigned)((row*128 + kk*64 + lq*16) ^ ((row & 7) << 4));
                bf16x8 af = *reinterpret_cast<const bf16x8*>(
                    reinterpret_cast<char*>(Abuf) + ab);
                #pragma unroll
                for (int n = 0; n < 2; ++n)
                    acc[m][n] = MFMA16(af, bfv[kk][n], acc[m][n]);
            }
        __syncthreads();
    }

    // epilogue: BN(eval) + leaky folded to v*A + B per column
    float As[2], Bsc[2];
    #pragma unroll
    for (int n = 0; n < 2; ++n) {
        const int c = col0 + wc*32 + n*16 + l15;
        const float inv = rsqrtf(rvar[c] + 1e-5f);
        As[n]  = inv * gamma[c];
        Bsc[n] = (b1[c] - rmean[c]) * As[n] + beta[c];
    }
    #pragma unroll
    for (int m = 0; m < 4; ++m) {
        const int rbase = row0 + wr*64 + m*16 + lq*4;
        #pragma unroll
        for (int n = 0; n < 2; ++n) {
            const int c = col0 + wc*32 + n*16 + l15;
            #pragma unroll
            for (int i = 0; i < 4; ++i) {
                float v = fmaf(acc[m][n][i], As[n], Bsc[n]);
                v = (v >= 0.f) ? v : 0.1f * v;
                h[(size_t)(rbase + i) * HIDD + c] = f2bf(v);
            }
        }
    }
}

// ---------- GEMM2 (8-phase fused, best-measured): e = h @ W2^T + b2; distances + L2 ----------
__global__ __launch_bounds__(512, 1)
void gemm2_mfma(const unsigned short* __restrict__ h,
                const unsigned short* __restrict__ W2bf,
                const float* __restrict__ b2,
                float* __restrict__ pdp, float* __restrict__ pdn,
                float* __restrict__ pl2)
{
    __shared__ char smem[114688];
    char* const Ab = smem;            // 2 x 24576: A[par][mrow 192][k 64]
    char* const Bb = smem + 49152;    // 2 x 32768: B[par][col 256][k 64]

    const int lin = blockIdx.x;       // 2048 = 8 XCD * 256
    const int wgid = (lin & 7) * 256 + (lin >> 3);
    const int cb = wgid & 3;
    const int rb = wgid >> 2;         // 0..511
    const int tid  = threadIdx.x;
    const int lane = tid & 63, w = tid >> 6;
    const int wm = w >> 2, wn = w & 3;
    const int row0 = rb * 64;
    const int col0 = cb * 256;
    const int l15 = lane & 15, lq = lane >> 4;

    f32x4 acc[6][4] = {};             // [mh*3 + stream][nf]

    auto issueA = [&](int k0, char* Adst) {
        #pragma unroll
        for (int i = 0; i < 3; ++i) {
            const int f = i * 512 + tid;       // 0..1535
            const int mrow = f >> 3, c = f & 7;
            const int mf = mrow >> 4, rr = mrow & 15;
            const int ss = mf % 3, rf = mf / 3;
            gload16(&h[((size_t)ss * NROWS + row0 + rf * 16 + rr) * HIDD + k0 + ((c ^ (mrow & 7)) << 3)],
                    Adst + f * 16);
        }
    };
    auto issueB = [&](int k0, char* Bdst) {
        #pragma unroll
        for (int i = 0; i < 4; ++i) {
            const int f = i * 512 + tid;
            const int col = f >> 3, c = f & 7;
            gload16(&W2bf[(size_t)(col0 + col) * HIDD + k0 + ((c ^ (col & 7)) << 3)],
                    Bdst + f * 16);
        }
    };
    auto readA = [&](bf16x8 (&a)[3][2], int mh, char* Abase) {
        #pragma unroll
        for (int mm = 0; mm < 3; ++mm) {
            const int row = (wm * 6 + mh * 3 + mm) * 16 + l15;
            const int swz = (row & 7) << 4;
            #pragma unroll
            for (int ks = 0; ks < 2; ++ks)
                a[mm][ks] = *reinterpret_cast<const bf16x8*>(
                    Abase + ((row * 128 + ks * 64 + lq * 16) ^ swz));
        }
    };
    auto readB = [&](bf16x8 (&b)[2][2], int nh, char* Bbase) {
        #pragma unroll
        for (int nn = 0; nn < 2; ++nn) {
            const int col = wn * 64 + (nh * 2 + nn) * 16 + l15;
            const int swz = (col & 7) << 4;
            #pragma unroll
            for (int ks = 0; ks < 2; ++ks)
                b[nn][ks] = *reinterpret_cast<const bf16x8*>(
                    Bbase + ((col * 128 + ks * 64 + lq * 16) ^ swz));
        }
    };

    // ---- prologue ----
    issueA(0, Ab);
    MEMFENCE;
    issueB(0, Bb);
    WAIT_VM(0);
    BAR();

    for (int t = 0; t < 8; ++t) {
        char* const Apt = Ab + (t & 1) * 24576;
        char* const Apn = Ab + ((t & 1) ^ 1) * 24576;
        char* const Bpt = Bb + (t & 1) * 32768;
        char* const Bpn = Bb + ((t & 1) ^ 1) * 32768;
        const int kn = ((t < 7) ? (t + 1) : 7) * 64;

        bf16x8 a[3][2], b[2][2], a2[3][2];
        // ---- P1: (0,0); issue A(t+1)+B(t+1) ----
        readA(a, 0, Apt);
        readB(b, 0, Bpt);
        issueA(kn, Apn);
        MEMFENCE;
        issueB(kn, Bpn);
        BAR(); WAIT_LGKM0; SCHEDB(); SP1();
        #pragma unroll
        for (int mm = 0; mm < 3; ++mm)
            #pragma unroll
            for (int nn = 0; nn < 2; ++nn)
                #pragma unroll
                for (int ks = 0; ks < 2; ++ks)
                    acc[mm][nn] = MFMA16(a[mm][ks], b[nn][ks], acc[mm][nn]);
        SP0(); BAR();
        // ---- P2: (0,1) ----
        readB(b, 1, Bpt);
        BAR(); WAIT_LGKM0; SCHEDB(); SP1();
        #pragma unroll
        for (int mm = 0; mm < 3; ++mm)
            #pragma unroll
            for (int nn = 0; nn < 2; ++nn)
                #pragma unroll
                for (int ks = 0; ks < 2; ++ks)
                    acc[mm][2 + nn] = MFMA16(a[mm][ks], b[nn][ks], acc[mm][2 + nn]);
        SP0(); BAR();
        // ---- P3: (1,1) ----
        readA(a2, 1, Apt);
        BAR(); WAIT_LGKM0; SCHEDB(); SP1();
        #pragma unroll
        for (int mm = 0; mm < 3; ++mm)
            #pragma unroll
            for (int nn = 0; nn < 2; ++nn)
                #pragma unroll
                for (int ks = 0; ks < 2; ++ks)
                    acc[3 + mm][2 + nn] = MFMA16(a2[mm][ks], b[nn][ks], acc[3 + mm][2 + nn]);
        SP0(); BAR();
        // ---- P4: (1,0); drain prefetches (3 phases of cover) ----
        readB(b, 0, Bpt);
        WAIT_VM(0);
        BAR(); WAIT_LGKM0; SCHEDB(); SP1();
        #pragma unroll
        for (int mm = 0; mm < 3; ++mm)
            #pragma unroll
            for (int nn = 0; nn < 2; ++nn)
                #pragma unroll
                for (int ks = 0; ks < 2; ++ks)
                    acc[3 + mm][nn] = MFMA16(a2[mm][ks], b[nn][ks], acc[3 + mm][nn]);
        SP0(); BAR();
    }

    // epilogue: distances + L2 (stream = acc row % 3), never materializing e
    float b2c[4];
    #pragma unroll
    for (int nf = 0; nf < 4; ++nf) b2c[nf] = b2[col0 + wn * 64 + nf * 16 + l15];
    float l2t = 0.f;
    #pragma unroll
    for (int mh = 0; mh < 2; ++mh) {
        const int rbase = row0 + (wm * 2 + mh) * 16 + lq * 4;
        #pragma unroll
        for (int i = 0; i < 4; ++i) {
            float dp = 0.f, dn = 0.f;
            #pragma unroll
            for (int nf = 0; nf < 4; ++nf) {
                const float ea = acc[mh * 3 + 0][nf][i] + b2c[nf];
                const float ep = acc[mh * 3 + 1][nf][i] + b2c[nf];
                const float en = acc[mh * 3 + 2][nf][i] + b2c[nf];
                dp += (ea - ep) * (ea - ep);
                dn += (ea - en) * (ea - en);
                l2t += ea * ea + ep * ep + en * en;
            }
            #pragma unroll
            for (int mm = 1; mm < 16; mm <<= 1) {
                dp += __shfl_xor(dp, mm);
                dn += __shfl_xor(dn, mm);
            }
            if (l15 == 0) {
                pdp[(size_t)(cb * 4 + wn) * NROWS + rbase + i] = dp;
                pdn[(size_t)(cb * 4 + wn) * NROWS + rbase + i] = dn;
            }
        }
    }
    #pragma unroll
    for (int mm = 1; mm < 64; mm <<= 1) l2t += __shfl_xor(l2t, mm);
    __syncthreads();
    float* const l2red = (float*)smem;
    if (lane == 0) l2red[w] = l2t;
    __syncthreads();
    if (tid == 0) {
        float t = 0.f;
        #pragma unroll
        for (int ww = 0; ww < 8; ++ww) t += l2red[ww];
        pl2[wgid] = t;
    }
}

// ---------- per-row margins ----------
__global__ __launch_bounds__(256)
void margins_kernel(const float* __restrict__ pdp, const float* __restrict__ pdn,
                    float* __restrict__ margins, float* __restrict__ dd)
{
    const int r = blockIdx.x * 256 + threadIdx.x;
    float dp2 = 0.f, dn2 = 0.f;
    #pragma unroll
    for (int q = 0; q < 16; ++q) {
        dp2 += pdp[(size_t)q * NROWS + r];
        dn2 += pdn[(size_t)q * NROWS + r];
    }
    dd[r] = dn2 - dp2;
    margins[r] = (dn2 < dp2) ? (sqrtf(dp2) - sqrtf(dn2)) : 0.f;
}

// ---------- final: l2 sum + radix-select (parallel digit scan) + neighbor pass + loss ----------
__global__ __launch_bounds__(1024)
void final_kernel(const float* __restrict__ pl2, int npl2,
                  const float* __restrict__ margins, const float* __restrict__ dd,
                  float* __restrict__ out)
{
    __shared__ unsigned hist[256];
    __shared__ float warp_red[16];
    __shared__ unsigned wsum[4];
    __shared__ unsigned sh_prefix;
    __shared__ int sh_k;
    __shared__ float sh_l2;
    __shared__ unsigned sh_cle;
    __shared__ unsigned sh_minAbove;
    const int tid = threadIdx.x;

    float l2 = 0.f;
    for (int i = tid; i < npl2; i += 1024) l2 += pl2[i];
    #pragma unroll
    for (int m = 1; m < 64; m <<= 1) l2 += __shfl_xor(l2, m);
    if ((tid & 63) == 0) warp_red[tid >> 6] = l2;
    __syncthreads();
    if (tid == 0) {
        float t = 0.f;
        for (int w = 0; w < 16; ++w) t += warp_red[w];
        sh_l2 = t;
        sh_k = 8191; sh_prefix = 0u;
        sh_cle = 0u; sh_minAbove = 0xFFFFFFFFu;
    }
    __syncthreads();

    for (int shift = 24; shift >= 0; shift -= 8) {
        if (tid < 256) hist[tid] = 0u;
        __syncthreads();
        const unsigned prefix = sh_prefix;
        const int kcur = sh_k;
        const unsigned mask = (shift == 24) ? 0u : (0xFFFFFFFFu << (shift + 8));
        for (int i = tid; i < NROWS; i += 1024) {
            const unsigned key = __float_as_uint(margins[i]);
            if (((key ^ prefix) & mask) == 0u)
                atomicAdd(&hist[(key >> shift) & 255u], 1u);
        }
        __syncthreads();
        unsigned v = 0, cme = 0;
        if (tid < 256) {
            cme = hist[tid];
            v = cme;
            #pragma unroll
            for (int off = 1; off < 64; off <<= 1) {
                unsigned tt = __shfl_up(v, off);
                if ((tid & 63) >= off) v += tt;
            }
            if ((tid & 63) == 63) wsum[tid >> 6] = v;
        }
        __syncthreads();
        if (tid < 256) {
            unsigned wo = 0;
            for (int i = 0; i < (tid >> 6); ++i) wo += wsum[i];
            const unsigned incl = v + wo;
            const unsigned excl = incl - cme;
            if ((unsigned)kcur >= excl && (unsigned)kcur < incl) {
                sh_prefix = prefix | ((unsigned)tid << shift);
                sh_k = kcur - (int)excl;
            }
        }
        __syncthreads();
    }
    const unsigned p1u = sh_prefix;

    unsigned lc = 0, lmin = 0xFFFFFFFFu;
    for (int i = tid; i < NROWS; i += 1024) {
        const unsigned key = __float_as_uint(margins[i]);
        if (key <= p1u) ++lc; else lmin = min(lmin, key);
    }
    #pragma unroll
    for (int m = 1; m < 64; m <<= 1) {
        lc += __shfl_xor(lc, m);
        lmin = min(lmin, (unsigned)__shfl_xor((int)lmin, m));
    }
    if ((tid & 63) == 0) {
        atomicAdd(&sh_cle, lc);
        atomicMin(&sh_minAbove, lmin);
    }
    __syncthreads();
    const float p1 = __uint_as_float(p1u);
    const float p2 = (sh_cle >= 8193u) ? p1 : __uint_as_float(sh_minAbove);
    const float margin = p1 + 0.75f * (p2 - p1);

    float ssum = 0.f;
    for (int i = tid; i < NROWS; i += 1024) {
        const float t = dd[i] + margin;
        ssum += (t > 0.f) ? t : 0.f;
    }
    #pragma unroll
    for (int m = 1; m < 64; m <<= 1) ssum += __shfl_xor(ssum, m);
    if ((tid & 63) == 0) warp_red[tid >> 6] = ssum;
    __syncthreads();
    if (tid == 0) {
        float S = 0.f;
        for (int w = 0; w < 16; ++w) S += warp_red[w];
        out[0] = S / (float)NROWS + 1e-3f * sh_l2 / (float)NROWS;
    }
}

extern "C" void kernel_launch(void* const* d_in, const int* in_sizes, int n_in,
                              void* d_out, int out_size, void* d_ws, size_t ws_size,
                              hipStream_t stream) {
    (void)in_sizes; (void)n_in; (void)out_size; (void)ws_size;
    const float* item = (const float*)d_in[0];
    const float* pos  = (const float*)d_in[1];
    const float* neg  = (const float*)d_in[2];
    const float* W1   = (const float*)d_in[3];
    const float* b1   = (const float*)d_in[4];
    const float* gam  = (const float*)d_in[5];
    const float* bet  = (const float*)d_in[6];
    const float* rmu  = (const float*)d_in[7];
    const float* rvr  = (const float*)d_in[8];
    const float* W2   = (const float*)d_in[9];
    const float* b2   = (const float*)d_in[10];

    char* ws = (char*)d_ws;
    unsigned short* h = (unsigned short*)ws;
    size_t off = (size_t)M3 * HIDD * sizeof(unsigned short);
    unsigned short* W1bf = (unsigned short*)(ws + off); off += (size_t)HIDD * DIM * 2;
    unsigned short* W2bf = (unsigned short*)(ws + off); off += (size_t)DIM * HIDD * 2;
    float* pdp = (float*)(ws + off); off += (size_t)16 * NROWS * 4;
    float* pdn = (float*)(ws + off); off += (size_t)16 * NROWS * 4;
    float* pl2 = (float*)(ws + off); off += (size_t)2048 * 4;
    float* margins = (float*)(ws + off); off += (size_t)NROWS * 4;
    float* dd = (float*)(ws + off); off += (size_t)NROWS * 4;

    const int n4each = HIDD * DIM / 4;           // 131072 float4s per weight
    cvt2_kernel<<<dim3(2 * n4each / 256), 256, 0, stream>>>(W1, W1bf, W2, W2bf, n4each);
    gemm1_mfma<<<dim3(3072), 512, 0, stream>>>(
        item, pos, neg, W1bf, b1, gam, bet, rmu, rvr, h);
    gemm2_mfma<<<dim3(2048), 512, 0, stream>>>(
        h, W2bf, b2, pdp, pdn, pl2);
    margins_kernel<<<dim3(NROWS/256), 256, 0, stream>>>(pdp, pdn, margins, dd);
    final_kernel<<<1, 1024, 0, stream>>>(pl2, 2048, margins, dd, (float*)d_out);
}